// Round 7
// baseline (237.403 us; speedup 1.0000x reference)
//
#include <hip/hip_runtime.h>
#include <stdint.h>

#define BATCH 8
#define SEQ 2048
#define DIM 1024
#define MTOT (BATCH * SEQ)   // 16384

typedef __attribute__((ext_vector_type(8))) short short8;
typedef __attribute__((ext_vector_type(8))) unsigned short ushort8;
typedef __attribute__((ext_vector_type(4))) float floatx4;

// ---------- helpers ----------

__device__ __forceinline__ unsigned short f2bf(float f) {
  union { float f; unsigned u; } c; c.f = f;
  unsigned u = c.u;
  return (unsigned short)((u + 0x7FFFu + ((u >> 16) & 1u)) >> 16);
}
__device__ __forceinline__ float bf2f(unsigned short h) {
  union { unsigned u; float f; } c; c.u = ((unsigned)h) << 16;
  return c.f;
}

__device__ __forceinline__ void gll16(const void* g, void* l) {
  __builtin_amdgcn_global_load_lds(
      (__attribute__((address_space(1))) void*)(uintptr_t)g,
      (__attribute__((address_space(3))) void*)(uintptr_t)l,
      16, 0, 0);
}

// pack hi16 of two fp32 (RTZ bf16): dst = (hi16(f1)<<16)|hi16(f0)
__device__ __forceinline__ unsigned pkbf(float f1, float f0) {
  return __builtin_amdgcn_perm(__builtin_bit_cast(unsigned, f1),
                               __builtin_bit_cast(unsigned, f0), 0x07060302u);
}

// ---------- cast B, W fp32->bf16 (RTNE) ----------

#define M4 (DIM * DIM / 4)    // 262144

__global__ __launch_bounds__(256) void castBW_kernel(
    const float* __restrict__ B, const float* __restrict__ W,
    unsigned short* __restrict__ Bb, unsigned short* __restrict__ Wb) {
  int i = blockIdx.x * 256 + threadIdx.x;
  const float4* s4;
  uint2* d2;
  int li;
  if (i < M4) { s4 = (const float4*)B; d2 = (uint2*)Bb; li = i; }
  else        { s4 = (const float4*)W; d2 = (uint2*)Wb; li = i - M4; }
  float4 v = s4[li];
  uint2 o;
  o.x = (unsigned)f2bf(v.x) | ((unsigned)f2bf(v.y) << 16);
  o.y = (unsigned)f2bf(v.z) | ((unsigned)f2bf(v.w) << 16);
  d2[li] = o;
}

// ---------- GEMM1 (direct fp32 x) fused with chunk scan + agg publish ------
// u[m][n] = sum_k x[m][k]*B[n][k]. A staged per-lane: fp32 global -> VGPR ->
// bf16 RTZ -> ds_write_b128 into the SAME swizzled LDS layout the fragment
// reads expect. B staged async via global_load_lds (source-column swizzle).
// Then per-column prefix scan over the 128-row chunk, h_local out bf16,
// chunk aggregate published. No cross-block sync anywhere.

__global__ __launch_bounds__(256) void gemm1_fused(
    const float* __restrict__ x,            // fp32 [M x 1024]
    const unsigned short* __restrict__ Bb,  // bf16 [1024 x 1024]
    unsigned short* __restrict__ u,         // h_local out bf16
    const float* __restrict__ Adiag,
    float* __restrict__ aggbuf) {           // [128][1024] fp32
  __shared__ unsigned short smem[16384];    // sA|sB (32 KB), reused as sC
  __shared__ float segsum[2][128];
  unsigned short* sA = smem;
  unsigned short* sB = smem + 8192;

  const int tid = threadIdx.x;
  const int wave = tid >> 6, lane = tid & 63;

  // round-2 XCD-aware tile remap (measured FETCH=ideal)
  const int id = blockIdx.x;
  const int xcd = id & 7, j = id >> 3;
  const int mt = xcd * 16 + (j >> 3);
  const int nt = j & 7;
  const size_t m0 = (size_t)mt * 128;
  const int n0 = nt * 128;

  floatx4 acc[4][4] = {};

  // A staging (per-lane): 4 threads/row, 16 fp32 each; 2 row-passes.
  const int arow = tid >> 2;              // 0..63
  const int ak0 = (tid & 3) * 16;         // k offset within 64
  const float* gx0 = x + (m0 + arow) * 1024 + ak0;
  const float* gx1 = x + (m0 + 64 + arow) * 1024 + ak0;
  const int ablk = (tid & 3) * 2;         // first 8-elem block index
  char* sAc = (char*)sA;
  const unsigned la0a = (unsigned)(arow * 128 + ((ablk ^ (arow & 7)) * 16));
  const unsigned la0b = (unsigned)(arow * 128 + (((ablk + 1) ^ (arow & 7)) * 16));
  const unsigned la1a = (unsigned)((64 + arow) * 128 + ((ablk ^ (arow & 7)) * 16));
  const unsigned la1b = (unsigned)((64 + arow) * 128 + (((ablk + 1) ^ (arow & 7)) * 16));

  // B staging (async): 4 rounds/wave, 8 rows/round, source-column swizzle.
  const int srow = wave * 8 + (lane >> 3);
  const int scol = (((lane & 7) ^ ((lane >> 3) & 7)) * 8);
  const unsigned short* gB = Bb + ((size_t)n0 + srow) * 1024 + scol;
  unsigned short* lB = sB + wave * 8 * 64;

  const int fr = lane & 15;
  const int frs = fr & 7;
  const int kb = lane >> 4;
  const int wm = (wave & 1) * 64, wn = (wave >> 1) * 64;

  for (int kt = 0; kt < 1024; kt += 64) {
#pragma unroll
    for (int r = 0; r < 4; ++r)
      gll16(gB + (size_t)r * 32 * 1024 + kt, lB + r * 32 * 64);

    // A: fp32 loads -> RTZ bf16 -> LDS (two 16B blocks per pass)
    float4 f0 = *(const float4*)(gx0 + kt);
    float4 f1 = *(const float4*)(gx0 + kt + 4);
    float4 f2 = *(const float4*)(gx0 + kt + 8);
    float4 f3 = *(const float4*)(gx0 + kt + 12);
    float4 f4 = *(const float4*)(gx1 + kt);
    float4 f5 = *(const float4*)(gx1 + kt + 4);
    float4 f6 = *(const float4*)(gx1 + kt + 8);
    float4 f7 = *(const float4*)(gx1 + kt + 12);
    uint4 w0 = {pkbf(f0.y, f0.x), pkbf(f0.w, f0.z),
                pkbf(f1.y, f1.x), pkbf(f1.w, f1.z)};
    uint4 w1 = {pkbf(f2.y, f2.x), pkbf(f2.w, f2.z),
                pkbf(f3.y, f3.x), pkbf(f3.w, f3.z)};
    uint4 w2 = {pkbf(f4.y, f4.x), pkbf(f4.w, f4.z),
                pkbf(f5.y, f5.x), pkbf(f5.w, f5.z)};
    uint4 w3 = {pkbf(f6.y, f6.x), pkbf(f6.w, f6.z),
                pkbf(f7.y, f7.x), pkbf(f7.w, f7.z)};
    *(uint4*)(sAc + la0a) = w0;
    *(uint4*)(sAc + la0b) = w1;
    *(uint4*)(sAc + la1a) = w2;
    *(uint4*)(sAc + la1b) = w3;

    asm volatile("s_waitcnt vmcnt(0)" ::: "memory");
    __syncthreads();
#pragma unroll
    for (int kk = 0; kk < 64; kk += 32) {
      short8 af[4], bfv[4];
#pragma unroll
      for (int i = 0; i < 4; ++i)
        af[i] = *(const short8*)(sA + (wm + i * 16 + fr) * 64 +
                                 ((((kk >> 3) + kb) ^ frs) * 8));
#pragma unroll
      for (int jj = 0; jj < 4; ++jj)
        bfv[jj] = *(const short8*)(sB + (wn + jj * 16 + fr) * 64 +
                                   ((((kk >> 3) + kb) ^ frs) * 8));
#pragma unroll
      for (int i = 0; i < 4; ++i)
#pragma unroll
        for (int jj = 0; jj < 4; ++jj)
          acc[i][jj] = __builtin_amdgcn_mfma_f32_16x16x32_bf16(
              af[i], bfv[jj], acc[i][jj], 0, 0, 0);
    }
    __syncthreads();
  }

  // stage u tile in LDS (C/D map: col=lane&15, row=(lane>>4)*4+reg)
  const int col = lane & 15;
  const int row4 = (lane >> 4) * 4;
  unsigned short* sC = smem;  // 128x128 bf16
#pragma unroll
  for (int i = 0; i < 4; ++i)
#pragma unroll
    for (int jj = 0; jj < 4; ++jj)
#pragma unroll
      for (int r = 0; r < 4; ++r)
        sC[(wm + i * 16 + row4 + r) * 128 + wn + jj * 16 + col] =
            f2bf(acc[i][jj][r]);
  __syncthreads();

  // chunk-local scan: 2 segments x 64 t per column
  const int colv = tid & 127;
  const int seg = tid >> 7;
  const float a = Adiag[n0 + colv];
  {
    float s = 0.f;
    const int t0 = seg * 64;
#pragma unroll 8
    for (int t = 0; t < 64; ++t) {
      int idx = (t0 + t) * 128 + colv;
      s = fmaf(a, s, bf2f(sC[idx]));
      sC[idx] = f2bf(s);
    }
    segsum[seg][colv] = s;
  }
  __syncthreads();

  // correct rows 64..127 with seg-0 end state; publish aggregate
  {
    float a2 = a * a, a4 = a2 * a2, a8 = a4 * a4, a16 = a8 * a8;
    float a32 = a16 * a16, a64 = a32 * a32;
    const float s0 = segsum[0][colv];
    const int t0 = 64 + seg * 32;
    float apow = seg ? a32 * a : a;
#pragma unroll 8
    for (int t = 0; t < 32; ++t) {
      int idx = (t0 + t) * 128 + colv;
      sC[idx] = f2bf(fmaf(apow, s0, bf2f(sC[idx])));
      apow *= a;
    }
    if (seg)
      aggbuf[(size_t)mt * 1024 + n0 + colv] = fmaf(a64, s0, segsum[1][colv]);
  }
  __syncthreads();

  // coalesced 16B h_local stores
#pragma unroll
  for (int s = 0; s < 8; ++s) {
    int row = wave * 32 + s * 4 + (lane >> 4);
    int c8 = (lane & 15) * 8;
    *(ushort8*)(u + (m0 + row) * (size_t)1024 + n0 + c8) =
        *(const ushort8*)(sC + row * 128 + c8);
  }
}

// ---------- apply+combine: carry from aggs (inline) then h correction ------
// Each block recomputes its chunk's carry from the <=15 preceding aggregates
// (L2-hot, 512 KB total). No ordering needed: kernel boundary is the barrier.

__global__ __launch_bounds__(256) void apply_kernel(
    unsigned short* __restrict__ u, const float* __restrict__ Adiag,
    const float* __restrict__ aggbuf) {
  const int id = blockIdx.x;                   // 0..2047
  const int xcd = id & 7, rem = id >> 3;
  const int mt = xcd * 16 + (rem >> 4);        // chunk 0..127 (gemm map)
  const int sub = rem & 15;                    // 8-row group within chunk
  const int tg = threadIdx.x >> 7;             // 0..1
  const int ch0 = (threadIdx.x & 127) * 8;
  const int b = mt >> 4, c = mt & 15;

  float a[8];
  *(float4*)&a[0] = *(const float4*)(Adiag + ch0);
  *(float4*)&a[4] = *(const float4*)(Adiag + ch0 + 4);
  float aL[8];
#pragma unroll
  for (int j = 0; j < 8; ++j) {
    float t = a[j];
    t *= t; t *= t; t *= t; t *= t; t *= t; t *= t; t *= t;  // a^128
    aL[j] = t;
  }

  // carry = sum_{p<c} agg[b,p] * (a^128)^(c-1-p)
  float cf[8];
#pragma unroll
  for (int j = 0; j < 8; ++j) cf[j] = 0.f;
  const float* ab = aggbuf + (size_t)(b * 16) * 1024 + ch0;
  for (int p = 0; p < c; ++p) {
    float4 g0 = *(const float4*)(ab + (size_t)p * 1024);
    float4 g1 = *(const float4*)(ab + (size_t)p * 1024 + 4);
    float g[8] = {g0.x, g0.y, g0.z, g0.w, g1.x, g1.y, g1.z, g1.w};
#pragma unroll
    for (int j = 0; j < 8; ++j) cf[j] = fmaf(aL[j], cf[j], g[j]);
  }

  const int tl = sub * 8 + tg * 4;  // local t of first row (0..124)
  float apow[8];
#pragma unroll
  for (int j = 0; j < 8; ++j)
    apow[j] = __builtin_amdgcn_exp2f(__builtin_amdgcn_logf(a[j]) *
                                     (float)(tl + 1));
  const size_t base = ((size_t)mt * 128 + tl) * DIM + ch0;
#pragma unroll
  for (int s = 0; s < 4; ++s) {
    ushort8 v = *(const ushort8*)(u + base + (size_t)s * DIM);
    ushort8 o;
#pragma unroll
    for (int j = 0; j < 8; ++j) {
      o[j] = f2bf(fmaf(apow[j], cf[j], bf2f(v[j])));
      apow[j] *= a[j];
    }
    *(ushort8*)(u + base + (size_t)s * DIM) = o;
  }
}

// ---------- GEMM2: y = h . W^T + bias (fp32 out) — round-2 verbatim --------

__global__ __launch_bounds__(256) void gemm2(
    const unsigned short* __restrict__ A, const unsigned short* __restrict__ B,
    float* __restrict__ C, const float* __restrict__ bias) {
  __shared__ unsigned short smem[16384];
  unsigned short* sA = smem;
  unsigned short* sB = smem + 8192;

  const int tid = threadIdx.x;
  const int wave = tid >> 6, lane = tid & 63;

  const int id = blockIdx.x;
  const int xcd = id & 7, j = id >> 3;
  const int mt = xcd * 16 + (j >> 3);
  const int nt = j & 7;
  const size_t m0 = (size_t)mt * 128;
  const int n0 = nt * 128;

  floatx4 acc[4][4] = {};

  const int srow = wave * 8 + (lane >> 3);
  const int scol = (((lane & 7) ^ ((lane >> 3) & 7)) * 8);
  const unsigned short* gA = A + (m0 + srow) * 1024 + scol;
  const unsigned short* gB = B + ((size_t)n0 + srow) * 1024 + scol;
  unsigned short* lA = sA + wave * 8 * 64;
  unsigned short* lB = sB + wave * 8 * 64;

  const int fr = lane & 15;
  const int frs = fr & 7;
  const int kb = lane >> 4;
  const int wm = (wave & 1) * 64, wn = (wave >> 1) * 64;

  for (int kt = 0; kt < 1024; kt += 64) {
#pragma unroll
    for (int r = 0; r < 4; ++r) {
      gll16(gA + (size_t)r * 32 * 1024 + kt, lA + r * 32 * 64);
      gll16(gB + (size_t)r * 32 * 1024 + kt, lB + r * 32 * 64);
    }
    asm volatile("s_waitcnt vmcnt(0)" ::: "memory");
    __syncthreads();
#pragma unroll
    for (int kk = 0; kk < 64; kk += 32) {
      short8 af[4], bfv[4];
#pragma unroll
      for (int i = 0; i < 4; ++i)
        af[i] = *(const short8*)(sA + (wm + i * 16 + fr) * 64 +
                                 ((((kk >> 3) + kb) ^ frs) * 8));
#pragma unroll
      for (int jj = 0; jj < 4; ++jj)
        bfv[jj] = *(const short8*)(sB + (wn + jj * 16 + fr) * 64 +
                                   ((((kk >> 3) + kb) ^ frs) * 8));
#pragma unroll
      for (int i = 0; i < 4; ++i)
#pragma unroll
        for (int jj = 0; jj < 4; ++jj)
          acc[i][jj] = __builtin_amdgcn_mfma_f32_16x16x32_bf16(
              af[i], bfv[jj], acc[i][jj], 0, 0, 0);
    }
    __syncthreads();
  }

  const int col = lane & 15;
  const int row4 = (lane >> 4) * 4;
#pragma unroll
  for (int i = 0; i < 4; ++i)
#pragma unroll
    for (int jj = 0; jj < 4; ++jj)
#pragma unroll
      for (int r = 0; r < 4; ++r) {
        size_t m = m0 + wm + i * 16 + row4 + r;
        int n = n0 + wn + jj * 16 + col;
        C[m * 1024 + n] = acc[i][jj][r] + bias[n];
      }
}

// ---------- launcher ----------

extern "C" void kernel_launch(void* const* d_in, const int* in_sizes, int n_in,
                              void* d_out, int out_size, void* d_ws,
                              size_t ws_size, hipStream_t stream) {
  const float* x    = (const float*)d_in[0];
  const float* A    = (const float*)d_in[1];
  const float* B    = (const float*)d_in[2];
  const float* W    = (const float*)d_in[3];
  const float* bias = (const float*)d_in[4];

  char* ws = (char*)d_ws;
  unsigned short* ubuf = (unsigned short*)ws;              // 32 MB (h_local->h)
  unsigned short* Bb   = (unsigned short*)(ws + 33554432); //  2 MB
  unsigned short* Wb   = (unsigned short*)(ws + 35651584); //  2 MB
  float* aggbuf        = (float*)(ws + 37748736);          // 512 KB

  castBW_kernel<<<2 * M4 / 256, 256, 0, stream>>>(B, W, Bb, Wb);

  gemm1_fused<<<1024, 256, 0, stream>>>(x, Bb, ubuf, A, aggbuf);

  apply_kernel<<<2048, 256, 0, stream>>>(ubuf, A, aggbuf);

  gemm2<<<1024, 256, 0, stream>>>(ubuf, Wb, (float*)d_out, bias);
}